// Round 20
// baseline (807.051 us; speedup 1.0000x reference)
//
#include <hip/hip_runtime.h>
#include <hip/hip_bf16.h>

#define DI __device__ __forceinline__

typedef unsigned int u32;
typedef unsigned short u16;
typedef __attribute__((ext_vector_type(8))) short short8;
typedef __attribute__((ext_vector_type(4))) float f32x4;

DI u16 f2bf(float f) {
  union { float f; u32 x; } t; t.f = f;
  u32 x = t.x;
  u32 r = (x + 0x7fffu + ((x >> 16) & 1u)) >> 16;   // RNE
  return (u16)r;
}
DI float bfu(u16 v) { union { u32 x; float f; } t; t.x = ((u32)v) << 16; return t.f; }

typedef __attribute__((address_space(3))) u32 lds_u32;
typedef const __attribute__((address_space(1))) u32 gbl_u32;
DI void gl_lds16(const u16* g, u16* l) {
  __builtin_amdgcn_global_load_lds((gbl_u32*)(const void*)g, (lds_u32*)(void*)l, 16, 0, 0);
}

// ---------------- pre: conv1 (MFMA) + w2 transform, one dispatch ----------------
__global__ __launch_bounds__(256) void pre_kernel(
    const float* __restrict__ x, const float* __restrict__ w1,
    const float* __restrict__ b1, const float* __restrict__ w2,
    u16* __restrict__ hT, u16* __restrict__ w2bT) {
  __shared__ union {
    struct { u16 xbf[784]; u16 im[400 * 96]; u16 ws[256 * 96]; } c1;
    float w2s[5184];
  } S;
  int tid = threadIdx.x;
  if (blockIdx.x >= 256) {
    int oc = blockIdx.x - 256;
    for (int ch = 0; ch < 4; ++ch) {
      __syncthreads();
      for (int t = tid; t < 5184; t += 256) S.w2s[t] = w2[(size_t)oc * 20736 + ch * 5184 + t];
      __syncthreads();
      for (int t = tid; t < 5184; t += 256) {
        int tap = t >> 6, icl = t & 63;
        w2bT[((size_t)tap * 256 + oc) * 256 + ch * 64 + icl] = f2bf(S.w2s[icl * 81 + tap]);
      }
    }
    return;
  }
  int b = blockIdx.x;
  int lane = tid & 63, wid = tid >> 6;
  const float* xb = x + (size_t)b * 784;
  for (int t = tid; t < 784; t += 256) S.c1.xbf[t] = f2bf(xb[t]);
  for (int t = tid; t < 20736; t += 256) {
    int oc = t / 81, kk = t % 81;
    int g = (kk >> 3) & 3, ph = (kk & 96) | (((g ^ ((oc >> 1) & 3)) << 3)) | (kk & 7);
    S.c1.ws[oc * 96 + ph] = f2bf(w1[t]);
  }
  for (int t = tid; t < 256 * 15; t += 256) {
    int oc = t / 15, kk = 81 + t % 15;
    int g = (kk >> 3) & 3, ph = (kk & 96) | (((g ^ ((oc >> 1) & 3)) << 3)) | (kk & 7);
    S.c1.ws[oc * 96 + ph] = 0;
  }
  __syncthreads();
  for (int pix = tid; pix < 400; pix += 256) {
    int py = pix / 20, px = pix - py * 20;
    int c2 = (pix >> 1) & 3;
    u16* dst = &S.c1.im[pix * 96];
    const u16* src = &S.c1.xbf[py * 28 + px];
#pragma unroll
    for (int ky = 0; ky < 9; ++ky)
#pragma unroll
      for (int kx = 0; kx < 9; ++kx) {
        int kk = ky * 9 + kx;
        int ph = (kk & 96) | ((((kk >> 3) & 3) ^ c2) << 3) | (kk & 7);
        dst[ph] = src[ky * 28 + kx];
      }
#pragma unroll
    for (int kk = 81; kk < 96; ++kk) {
      int ph = (kk & 96) | ((((kk >> 3) & 3) ^ c2) << 3) | (kk & 7);
      dst[ph] = 0;
    }
  }
  __syncthreads();
  int l15 = lane & 15, lh = lane >> 4;
  int slot8 = (lh ^ ((l15 >> 1) & 3)) << 3;
  short8 br[4][3];
  float bias[4];
#pragma unroll
  for (int ni = 0; ni < 4; ++ni) {
    int row = wid * 64 + ni * 16 + l15;
    bias[ni] = b1[row];
#pragma unroll
    for (int ksb = 0; ksb < 3; ++ksb)
      br[ni][ksb] = *(const short8*)&S.c1.ws[row * 96 + ksb * 32 + slot8];
  }
  for (int mt = 0; mt < 25; ++mt) {
    f32x4 acc[4];
#pragma unroll
    for (int ni = 0; ni < 4; ++ni) acc[ni] = (f32x4){0.f, 0.f, 0.f, 0.f};
    short8 ar[3];
#pragma unroll
    for (int ksb = 0; ksb < 3; ++ksb)
      ar[ksb] = *(const short8*)&S.c1.im[(mt * 16 + l15) * 96 + ksb * 32 + slot8];
#pragma unroll
    for (int ksb = 0; ksb < 3; ++ksb)
#pragma unroll
      for (int ni = 0; ni < 4; ++ni)
        acc[ni] = __builtin_amdgcn_mfma_f32_16x16x32_bf16(ar[ksb], br[ni][ksb], acc[ni], 0, 0, 0);
#pragma unroll
    for (int ni = 0; ni < 4; ++ni)
#pragma unroll
      for (int reg = 0; reg < 4; ++reg)
        hT[((size_t)b * 400 + mt * 16 + lh * 4 + reg) * 256 + wid * 64 + ni * 16 + l15] =
            f2bf(acc[ni][reg] + bias[ni]);
  }
}

// ---------------- conv2: BK=32 double-buffer 2-phase, K split 14 ways, 2 blocks/CU ----------------
// grid 504 = 8 XCD x 63. taps: ks<11 -> {ks, ks+14, ..., ks+70} (6), ks>=11 -> 5 taps.
__global__ __launch_bounds__(512, 4) void conv2_mfma_kernel(
    const u16* __restrict__ hT, const u16* __restrict__ w2bT,
    u16* __restrict__ pp) {
  __shared__ u16 Ab[2][8192]; // [256 b][32 k] x2 = 32 KB
  __shared__ u16 Bb[2][8192]; // [256 oc][32 k] x2 = 32 KB
  int bid = blockIdx.x;
  int xcd = bid & 7, rank = bid >> 3;
  int work = xcd * 63 + rank;
  int ks = work / 36, p = work % 36;
  int py = p / 6, px = p % 6;
  int tid = threadIdx.x, wid = tid >> 6, lane = tid & 63;
  int ntap = (ks < 11) ? 6 : 5;
  int nch = ntap * 8;   // chunks of K=32

  // staging: thread covers (row = tid>>2 and +128, gran = tid&3); source pre-swizzled
  // gran' = gran ^ ((row>>1)&3); (row>>1)&3 == (tid>>3)&3 for both halves (128 ≡ 0 mod 8 rows)
  int gsw = ((tid & 3) ^ ((tid >> 3) & 3)) * 8;
  int srow = tid >> 2;
  const u16* baseA0 = hT + (size_t)srow * 102400 + gsw;
  const u16* baseA1 = hT + (size_t)(128 + srow) * 102400 + gsw;
  const u16* baseB0 = w2bT + (size_t)srow * 256 + gsw;
  const u16* baseB1 = w2bT + (size_t)(128 + srow) * 256 + gsw;

#define STAGE(T, BUF) do {                                          \
    int tap_ = ((T) >> 3) * 14 + ks;                                \
    int icc_ = ((T) & 7) << 5;                                      \
    int pix_ = (2 * py + tap_ / 9) * 20 + (2 * px + tap_ % 9);      \
    int tofsA_ = pix_ * 256 + icc_;                                 \
    size_t tofsB_ = (size_t)tap_ * 65536 + icc_;                    \
    u16* la_ = &Ab[BUF][tid * 8];                                   \
    u16* lb_ = &Bb[BUF][tid * 8];                                   \
    gl_lds16(baseA0 + tofsA_, la_);                                 \
    gl_lds16(baseA1 + tofsA_, la_ + 4096);                          \
    gl_lds16(baseB0 + tofsB_, lb_);                                 \
    gl_lds16(baseB1 + tofsB_, lb_ + 4096);                          \
  } while (0)

  f32x4 acc[8][4];
#pragma unroll
  for (int i = 0; i < 8; ++i)
#pragma unroll
    for (int j = 0; j < 4; ++j) acc[i][j] = (f32x4){0.f, 0.f, 0.f, 0.f};

  int wr = wid >> 2, wc = wid & 3;
  int l15 = lane & 15, lh = lane >> 4;

  STAGE(0, 0);

  for (int ch = 0; ch < nch; ++ch) {
    __syncthreads();   // drains vmcnt -> current buf staged; prev compute done
    int buf = ch & 1;
    if (ch + 1 < nch) STAGE(ch + 1, buf ^ 1);
    const u16* A = &Ab[buf][0];
    const u16* B = &Bb[buf][0];
    short8 br[4];
#pragma unroll
    for (int ni = 0; ni < 4; ++ni) {
      int row = wc * 64 + ni * 16 + l15;
      br[ni] = *(const short8*)&B[row * 32 + ((lh ^ ((row >> 1) & 3)) * 8)];
    }
#pragma unroll
    for (int mi = 0; mi < 8; ++mi) {
      int row = wr * 128 + mi * 16 + l15;
      short8 ar = *(const short8*)&A[row * 32 + ((lh ^ ((row >> 1) & 3)) * 8)];
#pragma unroll
      for (int ni = 0; ni < 4; ++ni)
        acc[mi][ni] = __builtin_amdgcn_mfma_f32_16x16x32_bf16(ar, br[ni], acc[mi][ni], 0, 0, 0);
    }
  }
#undef STAGE

  u16* ppk = pp + (size_t)ks * 2359296 + (size_t)p * 256;
#pragma unroll
  for (int mi = 0; mi < 8; ++mi) {
    int b = wr * 128 + mi * 16 + lh * 4;
#pragma unroll
    for (int ni = 0; ni < 4; ++ni) {
      int oc = wc * 64 + ni * 16 + l15;
      union { u16 h[4]; uint2 u; } pk;
#pragma unroll
      for (int reg = 0; reg < 4; ++reg) pk.h[reg] = f2bf(acc[mi][ni][reg]);
      *(uint2*)&ppk[(size_t)oc * 9216 + b] = pk.u;
    }
  }
}

// ---------------- cwvgemm: softmax + CW + vGEMM + cb partial ----------------
__global__ __launch_bounds__(256) void cwvgemm_kernel(
    const float* __restrict__ bij, const float* __restrict__ W,
    const float* __restrict__ Wb, const u16* __restrict__ pp,
    const float* __restrict__ b2, float* __restrict__ prim2T,
    float* __restrict__ vp, float* __restrict__ cbp, int first) {
  __shared__ float cS[1152];
  __shared__ float cws[512];   // [4 loc][8 c][16 k]
  __shared__ float red[256];
  __shared__ float cbl[40][16];
  int ch = blockIdx.x, i = blockIdx.y, tid = threadIdx.x;
  if (first) {
    for (int n = tid; n < 1152; n += 256) cS[n] = 1.0f / 1152.0f;
  } else {
    const float* brow = bij + i * 1152;
    float m = -1e30f;
    for (int n = tid; n < 1152; n += 256) m = fmaxf(m, brow[n]);
    red[tid] = m; __syncthreads();
    for (int s = 128; s > 0; s >>= 1) { if (tid < s) red[tid] = fmaxf(red[tid], red[tid + s]); __syncthreads(); }
    m = red[0]; __syncthreads();
    float sum = 0.f;
    for (int n = tid; n < 1152; n += 256) sum += expf(brow[n] - m);
    red[tid] = sum; __syncthreads();
    for (int s = 128; s > 0; s >>= 1) { if (tid < s) red[tid] += red[tid + s]; __syncthreads(); }
    float inv = 1.0f / red[0];
    for (int n = tid; n < 1152; n += 256) cS[n] = expf(brow[n] - m) * inv;
  }
  __syncthreads();
  int loc_min = (i * 1152) / 10, loc_max = ((i + 1) * 1152 - 1) / 10;
  int lc0 = loc_min + ch * 4;
  for (int t = tid; t < 512; t += 256) {
    int ll = t >> 7, rem = t & 127, k = rem >> 3, cc = rem & 7;
    int loc = lc0 + ll;
    float a = 0.f;
    if (loc <= loc_max) {
      for (int io = 0; io < 10; ++io) {
        int mm = loc * 10 + io;
        if (mm / 1152 == i)
          a += cS[mm - i * 1152] * W[(size_t)io * 147456 + (size_t)loc * 128 + k * 8 + cc];
      }
    }
    cws[ll * 128 + cc * 16 + k] = a;
  }
  if (tid < 40) {
    int ll = tid / 10, io = tid % 10;
    int loc = lc0 + ll;
    float cv = 0.f;
    if (loc <= loc_max) {
      int mm = loc * 10 + io;
      if (mm / 1152 == i) cv = cS[mm - i * 1152];
    }
    if (cv != 0.f) {
      const float* wb = Wb + (size_t)io * 18432 + (size_t)loc * 16;
#pragma unroll
      for (int k = 0; k < 16; ++k) cbl[tid][k] = cv * wb[k];
    } else {
#pragma unroll
      for (int k = 0; k < 16; ++k) cbl[tid][k] = 0.f;
    }
  }
  __syncthreads();
  if (tid < 16) {
    float s = 0.f;
    for (int q = 0; q < 40; ++q) s += cbl[q][tid];
    cbp[(size_t)(ch * 10 + i) * 16 + tid] = s;
  }
  float acc[16];
#pragma unroll
  for (int k = 0; k < 16; ++k) acc[k] = 0.f;
  for (int ll = 0; ll < 4; ++ll) {
    int loc = lc0 + ll;
    if (loc > loc_max) break;
    const float* cw = cws + ll * 128;
#pragma unroll
    for (int cc = 0; cc < 8; ++cc) {
      int flat = loc * 8 + cc;
      float pvv;
      if (first) {
        pvv = b2[flat / 36];
#pragma unroll
        for (int ks = 0; ks < 14; ++ks)
          pvv += bfu(pp[(size_t)ks * 2359296 + (size_t)flat * 256 + tid]);
        prim2T[(size_t)flat * 256 + tid] = pvv;
      } else {
        pvv = prim2T[(size_t)flat * 256 + tid];
      }
      float4 a0 = *(const float4*)&cw[cc * 16];
      float4 a1 = *(const float4*)&cw[cc * 16 + 4];
      float4 a2 = *(const float4*)&cw[cc * 16 + 8];
      float4 a3 = *(const float4*)&cw[cc * 16 + 12];
      acc[0] += pvv * a0.x; acc[1] += pvv * a0.y; acc[2] += pvv * a0.z; acc[3] += pvv * a0.w;
      acc[4] += pvv * a1.x; acc[5] += pvv * a1.y; acc[6] += pvv * a1.z; acc[7] += pvv * a1.w;
      acc[8] += pvv * a2.x; acc[9] += pvv * a2.y; acc[10] += pvv * a2.z; acc[11] += pvv * a2.w;
      acc[12] += pvv * a3.x; acc[13] += pvv * a3.y; acc[14] += pvv * a3.z; acc[15] += pvv * a3.w;
    }
  }
  float* dst = vp + ((size_t)(ch * 10 + i) * 256 + tid) * 16;
#pragma unroll
  for (int k = 0; k < 16; ++k) dst[k] = acc[k];
}

// ---------------- vred: combine 32 vp chunks + cb -> vpre; partials ssp/svp ----------------
__global__ __launch_bounds__(256) void vred_kernel(
    const float* __restrict__ vp, const float* __restrict__ cbp,
    float* __restrict__ vpre, float* __restrict__ ssp, float* __restrict__ svp) {
  __shared__ float red[256];
  __shared__ float sh[16][17];
  int bs = blockIdx.x, i = blockIdx.y, tid = threadIdx.x;
  int bl = tid >> 4, k = tid & 15;
  int b = bs * 16 + bl;
  float a = 0.f;
  for (int ch = 0; ch < 32; ++ch) a += vp[((size_t)(ch * 10 + i) * 256 + b) * 16 + k];
  float cb = 0.f;
  for (int ch = 0; ch < 32; ++ch) cb += cbp[(size_t)(ch * 10 + i) * 16 + k];
  a += cb;
  vpre[((size_t)i * 256 + b) * 16 + k] = a;
  red[tid] = a * a;
  sh[bl][k] = a;
  __syncthreads();
  for (int s = 128; s > 0; s >>= 1) { if (tid < s) red[tid] += red[tid + s]; __syncthreads(); }
  for (int s = 8; s > 0; s >>= 1) { if (bl < s) sh[bl][k] += sh[bl + s][k]; __syncthreads(); }
  if (tid == 0) ssp[i * 16 + bs] = red[0];
  if (tid < 16) svp[(size_t)(i * 16 + bs) * 16 + tid] = sh[0][tid];
}

// ---------------- pv_bij: inline squash-scale from partials + P + bij ----------------
__global__ __launch_bounds__(256) void pv_bij_kernel(
    const float* __restrict__ vpre, const float* __restrict__ ssp,
    const float* __restrict__ svp, const float* __restrict__ prim2T,
    const float* __restrict__ W, const float* __restrict__ Wb,
    float* __restrict__ bij, int first) {
  __shared__ float ps[32 * 260];      // [flat_l][b] padded
  __shared__ float vs[2 * 16 * 260];  // [cl][k][b] padded
  __shared__ float Ps[32][32];        // [flat_l][slot*16+k]
  __shared__ float scl[2];
  __shared__ float svl[2][16];
  int blk = blockIdx.x, tid = threadIdx.x;
  int loc0 = blk * 4;
  int I = (loc0 * 10) / 1152;
  if (tid < 2) {
    int cls = I + tid;
    float ss = 0.f;
    if (cls <= 9)
      for (int q = 0; q < 16; ++q) ss += ssp[cls * 16 + q];
    float nrm = sqrtf(ss);
    scl[tid] = (cls <= 9 && nrm > 0.f) ? nrm / (1.f + nrm * nrm) : 0.f;
  }
  if (tid < 32) {
    int cl = tid >> 4, k = tid & 15;
    int cls = I + cl;
    float s = 0.f;
    if (cls <= 9)
      for (int q = 0; q < 16; ++q) s += svp[(size_t)(cls * 16 + q) * 16 + k];
    svl[cl][k] = s;
  }
  for (int t = tid; t < 2048; t += 256) {
    int row = t >> 6, seg = t & 63;
    float4 a = *(const float4*)(prim2T + (size_t)(loc0 * 8 + row) * 256 + seg * 4);
    *(float4*)&ps[row * 260 + seg * 4] = a;
  }
  __syncthreads();
  for (int cl = 0; cl < 2; ++cl) {
    int cls = I + cl;
    float sc = scl[cl];
    for (int t = tid; t < 4096; t += 256) {
      int b = t >> 4, k = t & 15;
      float val = (cls <= 9) ? vpre[(size_t)cls * 4096 + t] * sc : 0.f;
      vs[(cl * 16 + k) * 260 + b] = val;
    }
  }
  __syncthreads();
  {
    int k = tid & 15, fs = tid >> 4;
    const float4* ps4 = (const float4*)ps;
    const float4* vs4 = (const float4*)vs;
#pragma unroll
    for (int q = 0; q < 4; ++q) {
      int flat_l = fs * 2 + (q & 1);
      int slot = q >> 1;
      int loc = loc0 + (flat_l >> 3);
      int cls = (loc * 10) / 1152 + slot;
      int cl_idx = cls - I;
      if (cl_idx <= 1 && cls <= 9) {
        float a = 0.f;
        int bp = flat_l * 65, bv = (cl_idx * 16 + k) * 65;
        for (int b4 = 0; b4 < 64; ++b4) {
          float4 p4 = ps4[bp + b4];
          float4 w4 = vs4[bv + b4];
          a += p4.x * w4.x + p4.y * w4.y + p4.z * w4.z + p4.w * w4.w;
        }
        Ps[flat_l][slot * 16 + k] = a;
      }
    }
  }
  __syncthreads();
  if (tid < 40) {
    int ll = tid / 10, io = tid % 10;
    int loc = loc0 + ll;
    int m = loc * 10 + io;
    int i = m / 1152;
    int slot = i - (loc * 10) / 1152;
    int cl = i - I;
    const float* wrow = W + (size_t)io * 147456 + (size_t)loc * 128;
    float s = 0.f;
#pragma unroll
    for (int k = 0; k < 16; ++k) {
      float4 w0 = *(const float4*)(wrow + k * 8);
      float4 w1 = *(const float4*)(wrow + k * 8 + 4);
      s += w0.x * Ps[ll * 8 + 0][slot * 16 + k] + w0.y * Ps[ll * 8 + 1][slot * 16 + k]
         + w0.z * Ps[ll * 8 + 2][slot * 16 + k] + w0.w * Ps[ll * 8 + 3][slot * 16 + k];
      s += w1.x * Ps[ll * 8 + 4][slot * 16 + k] + w1.y * Ps[ll * 8 + 5][slot * 16 + k]
         + w1.z * Ps[ll * 8 + 6][slot * 16 + k] + w1.w * Ps[ll * 8 + 7][slot * 16 + k];
    }
    const float* wbr = Wb + (size_t)io * 18432 + (size_t)loc * 16;
    float scsv = scl[cl];
#pragma unroll
    for (int k = 0; k < 16; ++k) s += wbr[k] * (scsv * svl[cl][k]);
    bij[m] = first ? s : (bij[m] + s);
  }
}

// ---------------- outw: final squash + output write ----------------
__global__ __launch_bounds__(256) void outw_kernel(
    const float* __restrict__ vpre, const float* __restrict__ ssp,
    float* __restrict__ out) {
  int i = blockIdx.x, tid = threadIdx.x;
  float ss = 0.f;
  for (int q = 0; q < 16; ++q) ss += ssp[i * 16 + q];
  float nrm = sqrtf(ss);
  float scale = (nrm > 0.f) ? nrm / (1.f + nrm * nrm) : 0.f;
  for (int t = tid; t < 4096; t += 256)
    out[(size_t)i * 4096 + t] = vpre[(size_t)i * 4096 + t] * scale;
}

extern "C" void kernel_launch(void* const* d_in, const int* in_sizes, int n_in,
                              void* d_out, int out_size, void* d_ws, size_t ws_size,
                              hipStream_t stream) {
  const float* x  = (const float*)d_in[0];
  const float* w1 = (const float*)d_in[1];
  const float* b1 = (const float*)d_in[2];
  const float* w2 = (const float*)d_in[3];
  const float* b2 = (const float*)d_in[4];
  const float* W  = (const float*)d_in[5];
  const float* Wb = (const float*)d_in[6];
  float* out = (float*)d_out;

  // workspace layout (~150 MB)
  u16*   hT     = (u16*)d_ws;                    // 26,214,400 u16
  u16*   w2bT   = hT + 26214400;                 //  5,308,416 u16
  u16*   pp     = w2bT + 5308416;                // 14*2,359,296 u16 (bf16 partials)
  float* prim2T = (float*)(pp + 14 * 2359296);   //  2,359,296 f
  float* vp     = prim2T + 2359296;              //  1,310,720 f
  float* vpre   = vp + 1310720;                  //     40,960 f
  float* bij    = vpre + 40960;                  //     11,520 f
  float* ssp    = bij + 11520;                   //        160 f
  float* svp    = ssp + 160;                     //      2,560 f
  float* cbp    = svp + 2560;                    //      5,120 f

  pre_kernel<<<512, 256, 0, stream>>>(x, w1, b1, w2, hT, w2bT);
  conv2_mfma_kernel<<<504, 512, 0, stream>>>(hT, w2bT, pp);

  for (int r = 0; r < 3; ++r) {
    cwvgemm_kernel<<<dim3(32, 10), 256, 0, stream>>>(bij, W, Wb, pp, b2, prim2T, vp, cbp,
                                                     r == 0 ? 1 : 0);
    vred_kernel<<<dim3(16, 10), 256, 0, stream>>>(vp, cbp, vpre, ssp, svp);
    if (r < 2) {
      pv_bij_kernel<<<288, 256, 0, stream>>>(vpre, ssp, svp, prim2T, W, Wb, bij,
                                             r == 0 ? 1 : 0);
    } else {
      outw_kernel<<<10, 256, 0, stream>>>(vpre, ssp, out);
    }
  }
}

// Round 21
// 294.991 us; speedup vs baseline: 2.7359x; 2.7359x over previous
//
#include <hip/hip_runtime.h>
#include <hip/hip_bf16.h>

#define DI __device__ __forceinline__

typedef unsigned int u32;
typedef unsigned short u16;
typedef __attribute__((ext_vector_type(8))) short short8;
typedef __attribute__((ext_vector_type(4))) float f32x4;

DI u16 f2bf(float f) {
  union { float f; u32 x; } t; t.f = f;
  u32 x = t.x;
  u32 r = (x + 0x7fffu + ((x >> 16) & 1u)) >> 16;   // RNE
  return (u16)r;
}
DI float bfu(u16 v) { union { u32 x; float f; } t; t.x = ((u32)v) << 16; return t.f; }

typedef __attribute__((address_space(3))) u32 lds_u32;
typedef const __attribute__((address_space(1))) u32 gbl_u32;
DI void gl_lds16(const u16* g, u16* l) {
  __builtin_amdgcn_global_load_lds((gbl_u32*)(const void*)g, (lds_u32*)(void*)l, 16, 0, 0);
}

// ---------------- pre: conv1 (MFMA) + w2 transform, one dispatch ----------------
__global__ __launch_bounds__(256) void pre_kernel(
    const float* __restrict__ x, const float* __restrict__ w1,
    const float* __restrict__ b1, const float* __restrict__ w2,
    u16* __restrict__ hT, u16* __restrict__ w2bT) {
  __shared__ union {
    struct { u16 xbf[784]; u16 im[400 * 96]; u16 ws[256 * 96]; } c1;
    float w2s[5184];
  } S;
  int tid = threadIdx.x;
  if (blockIdx.x >= 256) {
    int oc = blockIdx.x - 256;
    for (int ch = 0; ch < 4; ++ch) {
      __syncthreads();
      for (int t = tid; t < 5184; t += 256) S.w2s[t] = w2[(size_t)oc * 20736 + ch * 5184 + t];
      __syncthreads();
      for (int t = tid; t < 5184; t += 256) {
        int tap = t >> 6, icl = t & 63;
        w2bT[((size_t)tap * 256 + oc) * 256 + ch * 64 + icl] = f2bf(S.w2s[icl * 81 + tap]);
      }
    }
    return;
  }
  int b = blockIdx.x;
  int lane = tid & 63, wid = tid >> 6;
  const float* xb = x + (size_t)b * 784;
  for (int t = tid; t < 784; t += 256) S.c1.xbf[t] = f2bf(xb[t]);
  for (int t = tid; t < 20736; t += 256) {
    int oc = t / 81, kk = t % 81;
    int g = (kk >> 3) & 3, ph = (kk & 96) | (((g ^ ((oc >> 1) & 3)) << 3)) | (kk & 7);
    S.c1.ws[oc * 96 + ph] = f2bf(w1[t]);
  }
  for (int t = tid; t < 256 * 15; t += 256) {
    int oc = t / 15, kk = 81 + t % 15;
    int g = (kk >> 3) & 3, ph = (kk & 96) | (((g ^ ((oc >> 1) & 3)) << 3)) | (kk & 7);
    S.c1.ws[oc * 96 + ph] = 0;
  }
  __syncthreads();
  for (int pix = tid; pix < 400; pix += 256) {
    int py = pix / 20, px = pix - py * 20;
    int c2 = (pix >> 1) & 3;
    u16* dst = &S.c1.im[pix * 96];
    const u16* src = &S.c1.xbf[py * 28 + px];
#pragma unroll
    for (int ky = 0; ky < 9; ++ky)
#pragma unroll
      for (int kx = 0; kx < 9; ++kx) {
        int kk = ky * 9 + kx;
        int ph = (kk & 96) | ((((kk >> 3) & 3) ^ c2) << 3) | (kk & 7);
        dst[ph] = src[ky * 28 + kx];
      }
#pragma unroll
    for (int kk = 81; kk < 96; ++kk) {
      int ph = (kk & 96) | ((((kk >> 3) & 3) ^ c2) << 3) | (kk & 7);
      dst[ph] = 0;
    }
  }
  __syncthreads();
  int l15 = lane & 15, lh = lane >> 4;
  int slot8 = (lh ^ ((l15 >> 1) & 3)) << 3;
  short8 br[4][3];
  float bias[4];
#pragma unroll
  for (int ni = 0; ni < 4; ++ni) {
    int row = wid * 64 + ni * 16 + l15;
    bias[ni] = b1[row];
#pragma unroll
    for (int ksb = 0; ksb < 3; ++ksb)
      br[ni][ksb] = *(const short8*)&S.c1.ws[row * 96 + ksb * 32 + slot8];
  }
  for (int mt = 0; mt < 25; ++mt) {
    f32x4 acc[4];
#pragma unroll
    for (int ni = 0; ni < 4; ++ni) acc[ni] = (f32x4){0.f, 0.f, 0.f, 0.f};
    short8 ar[3];
#pragma unroll
    for (int ksb = 0; ksb < 3; ++ksb)
      ar[ksb] = *(const short8*)&S.c1.im[(mt * 16 + l15) * 96 + ksb * 32 + slot8];
#pragma unroll
    for (int ksb = 0; ksb < 3; ++ksb)
#pragma unroll
      for (int ni = 0; ni < 4; ++ni)
        acc[ni] = __builtin_amdgcn_mfma_f32_16x16x32_bf16(ar[ksb], br[ni][ksb], acc[ni], 0, 0, 0);
#pragma unroll
    for (int ni = 0; ni < 4; ++ni)
#pragma unroll
      for (int reg = 0; reg < 4; ++reg)
        hT[((size_t)b * 400 + mt * 16 + lh * 4 + reg) * 256 + wid * 64 + ni * 16 + l15] =
            f2bf(acc[ni][reg] + bias[ni]);
  }
}

// ---------------- conv2: proven 2-phase schedule, 252 blocks, XCD remap; bf16 partials ----------------
__global__ __launch_bounds__(512, 2) void conv2_mfma_kernel(
    const u16* __restrict__ hT, const u16* __restrict__ w2bT,
    u16* __restrict__ pp) {
  __shared__ u16 Ab[2][16384]; // [256 b][64 k]
  __shared__ u16 Bb[2][16384]; // [256 oc][64 k]
  int bid = blockIdx.x;
  int xcd = bid & 7, rank = bid >> 3;
  int work = (xcd < 4 ? xcd * 32 : 128 + (xcd - 4) * 31) + rank;
  int ks = work / 36, p = work % 36;
  int py = p / 6, px = p % 6;
  int tid = threadIdx.x, wid = tid >> 6, lane = tid & 63;
  int ntap = (ks < 4) ? 12 : 11;
  int nch = ntap * 4;

  const u16* srcA[4];
  const u16* srcB[4];
#pragma unroll
  for (int c = 0; c < 4; ++c) {
    int row = wid * 32 + c * 8 + (lane >> 3);
    int gsw = ((lane & 7) ^ (row & 7)) * 8;
    srcA[c] = hT + (size_t)row * 102400 + gsw;   // + pix*256 + icc*64
    srcB[c] = w2bT + (size_t)row * 256 + gsw;    // + tap*65536 + icc*64
  }

  f32x4 acc[8][4];
#pragma unroll
  for (int i = 0; i < 8; ++i)
#pragma unroll
    for (int j = 0; j < 4; ++j) acc[i][j] = (f32x4){0.f, 0.f, 0.f, 0.f};

  int wr = wid >> 2, wc = wid & 3;
  int l15 = lane & 15, lh = lane >> 4;

  {
    int tap = ks;
    int pix = (2 * py + tap / 9) * 20 + (2 * px + tap % 9);
    int tofsA = pix * 256;
    size_t tofsB = (size_t)tap * 65536;
#pragma unroll
    for (int c = 0; c < 4; ++c) {
      gl_lds16(srcA[c] + tofsA, &Ab[0][(wid * 32 + c * 8) * 64]);
      gl_lds16(srcB[c] + tofsB, &Bb[0][(wid * 32 + c * 8) * 64]);
    }
  }

  for (int ch = 0; ch < nch; ++ch) {
    __syncthreads();
    int buf = ch & 1;
    if (ch + 1 < nch) {
      int nc2 = ch + 1;
      int tap = (nc2 >> 2) * 7 + ks;
      int icc = nc2 & 3;
      int pix = (2 * py + tap / 9) * 20 + (2 * px + tap % 9);
      int tofsA = pix * 256 + icc * 64;
      size_t tofsB = (size_t)tap * 65536 + icc * 64;
#pragma unroll
      for (int c = 0; c < 4; ++c) {
        gl_lds16(srcA[c] + tofsA, &Ab[buf ^ 1][(wid * 32 + c * 8) * 64]);
        gl_lds16(srcB[c] + tofsB, &Bb[buf ^ 1][(wid * 32 + c * 8) * 64]);
      }
    }
#pragma unroll
    for (int kk = 0; kk < 2; ++kk) {
      int g = kk * 4 + lh;
      short8 br[4];
#pragma unroll
      for (int ni = 0; ni < 4; ++ni) {
        int row = wc * 64 + ni * 16 + l15;
        br[ni] = *(const short8*)&Bb[buf][row * 64 + ((g ^ (row & 7)) * 8)];
      }
#pragma unroll
      for (int mi = 0; mi < 8; ++mi) {
        int row = wr * 128 + mi * 16 + l15;
        short8 ar = *(const short8*)&Ab[buf][row * 64 + ((g ^ (row & 7)) * 8)];
#pragma unroll
        for (int ni = 0; ni < 4; ++ni)
          acc[mi][ni] = __builtin_amdgcn_mfma_f32_16x16x32_bf16(ar, br[ni], acc[mi][ni], 0, 0, 0);
      }
    }
  }

  u16* ppk = pp + (size_t)ks * 2359296 + (size_t)p * 256;
#pragma unroll
  for (int mi = 0; mi < 8; ++mi) {
    int b = wr * 128 + mi * 16 + lh * 4;
#pragma unroll
    for (int ni = 0; ni < 4; ++ni) {
      int oc = wc * 64 + ni * 16 + l15;
      union { u16 h[4]; uint2 u; } pk;
#pragma unroll
      for (int reg = 0; reg < 4; ++reg) pk.h[reg] = f2bf(acc[mi][ni][reg]);
      *(uint2*)&ppk[(size_t)oc * 9216 + b] = pk.u;
    }
  }
}

// ---------------- cwvgemm: softmax + CW + vGEMM + cb partial ----------------
__global__ __launch_bounds__(256) void cwvgemm_kernel(
    const float* __restrict__ bij, const float* __restrict__ W,
    const float* __restrict__ Wb, const u16* __restrict__ pp,
    const float* __restrict__ b2, float* __restrict__ prim2T,
    float* __restrict__ vp, float* __restrict__ cbp, int first) {
  __shared__ float cS[1152];
  __shared__ float cws[512];   // [4 loc][8 c][16 k]
  __shared__ float red[256];
  __shared__ float cbl[40][16];
  int ch = blockIdx.x, i = blockIdx.y, tid = threadIdx.x;
  if (first) {
    for (int n = tid; n < 1152; n += 256) cS[n] = 1.0f / 1152.0f;
  } else {
    const float* brow = bij + i * 1152;
    float m = -1e30f;
    for (int n = tid; n < 1152; n += 256) m = fmaxf(m, brow[n]);
    red[tid] = m; __syncthreads();
    for (int s = 128; s > 0; s >>= 1) { if (tid < s) red[tid] = fmaxf(red[tid], red[tid + s]); __syncthreads(); }
    m = red[0]; __syncthreads();
    float sum = 0.f;
    for (int n = tid; n < 1152; n += 256) sum += expf(brow[n] - m);
    red[tid] = sum; __syncthreads();
    for (int s = 128; s > 0; s >>= 1) { if (tid < s) red[tid] += red[tid + s]; __syncthreads(); }
    float inv = 1.0f / red[0];
    for (int n = tid; n < 1152; n += 256) cS[n] = expf(brow[n] - m) * inv;
  }
  __syncthreads();
  int loc_min = (i * 1152) / 10, loc_max = ((i + 1) * 1152 - 1) / 10;
  int lc0 = loc_min + ch * 4;
  for (int t = tid; t < 512; t += 256) {
    int ll = t >> 7, rem = t & 127, k = rem >> 3, cc = rem & 7;
    int loc = lc0 + ll;
    float a = 0.f;
    if (loc <= loc_max) {
      for (int io = 0; io < 10; ++io) {
        int mm = loc * 10 + io;
        if (mm / 1152 == i)
          a += cS[mm - i * 1152] * W[(size_t)io * 147456 + (size_t)loc * 128 + k * 8 + cc];
      }
    }
    cws[ll * 128 + cc * 16 + k] = a;
  }
  if (tid < 40) {
    int ll = tid / 10, io = tid % 10;
    int loc = lc0 + ll;
    float cv = 0.f;
    if (loc <= loc_max) {
      int mm = loc * 10 + io;
      if (mm / 1152 == i) cv = cS[mm - i * 1152];
    }
    if (cv != 0.f) {
      const float* wb = Wb + (size_t)io * 18432 + (size_t)loc * 16;
#pragma unroll
      for (int k = 0; k < 16; ++k) cbl[tid][k] = cv * wb[k];
    } else {
#pragma unroll
      for (int k = 0; k < 16; ++k) cbl[tid][k] = 0.f;
    }
  }
  __syncthreads();
  if (tid < 16) {
    float s = 0.f;
    for (int q = 0; q < 40; ++q) s += cbl[q][tid];
    cbp[(size_t)(ch * 10 + i) * 16 + tid] = s;
  }
  float acc[16];
#pragma unroll
  for (int k = 0; k < 16; ++k) acc[k] = 0.f;
  for (int ll = 0; ll < 4; ++ll) {
    int loc = lc0 + ll;
    if (loc > loc_max) break;
    const float* cw = cws + ll * 128;
#pragma unroll
    for (int cc = 0; cc < 8; ++cc) {
      int flat = loc * 8 + cc;
      float pvv;
      if (first) {
        pvv = b2[flat / 36];
#pragma unroll
        for (int ks = 0; ks < 7; ++ks)
          pvv += bfu(pp[(size_t)ks * 2359296 + (size_t)flat * 256 + tid]);
        prim2T[(size_t)flat * 256 + tid] = pvv;
      } else {
        pvv = prim2T[(size_t)flat * 256 + tid];
      }
      float4 a0 = *(const float4*)&cw[cc * 16];
      float4 a1 = *(const float4*)&cw[cc * 16 + 4];
      float4 a2 = *(const float4*)&cw[cc * 16 + 8];
      float4 a3 = *(const float4*)&cw[cc * 16 + 12];
      acc[0] += pvv * a0.x; acc[1] += pvv * a0.y; acc[2] += pvv * a0.z; acc[3] += pvv * a0.w;
      acc[4] += pvv * a1.x; acc[5] += pvv * a1.y; acc[6] += pvv * a1.z; acc[7] += pvv * a1.w;
      acc[8] += pvv * a2.x; acc[9] += pvv * a2.y; acc[10] += pvv * a2.z; acc[11] += pvv * a2.w;
      acc[12] += pvv * a3.x; acc[13] += pvv * a3.y; acc[14] += pvv * a3.z; acc[15] += pvv * a3.w;
    }
  }
  float* dst = vp + ((size_t)(ch * 10 + i) * 256 + tid) * 16;
#pragma unroll
  for (int k = 0; k < 16; ++k) dst[k] = acc[k];
}

// ---------------- vred: combine 32 vp chunks + cb -> vpre; partials ssp/svp ----------------
__global__ __launch_bounds__(256) void vred_kernel(
    const float* __restrict__ vp, const float* __restrict__ cbp,
    float* __restrict__ vpre, float* __restrict__ ssp, float* __restrict__ svp) {
  __shared__ float red[256];
  __shared__ float sh[16][17];
  int bs = blockIdx.x, i = blockIdx.y, tid = threadIdx.x;
  int bl = tid >> 4, k = tid & 15;
  int b = bs * 16 + bl;
  float a = 0.f;
  for (int ch = 0; ch < 32; ++ch) a += vp[((size_t)(ch * 10 + i) * 256 + b) * 16 + k];
  float cb = 0.f;
  for (int ch = 0; ch < 32; ++ch) cb += cbp[(size_t)(ch * 10 + i) * 16 + k];
  a += cb;
  vpre[((size_t)i * 256 + b) * 16 + k] = a;
  red[tid] = a * a;
  sh[bl][k] = a;
  __syncthreads();
  for (int s = 128; s > 0; s >>= 1) { if (tid < s) red[tid] += red[tid + s]; __syncthreads(); }
  for (int s = 8; s > 0; s >>= 1) { if (bl < s) sh[bl][k] += sh[bl + s][k]; __syncthreads(); }
  if (tid == 0) ssp[i * 16 + bs] = red[0];
  if (tid < 16) svp[(size_t)(i * 16 + bs) * 16 + tid] = sh[0][tid];
}

// ---------------- pv_bij: inline squash-scale from partials + P + bij ----------------
__global__ __launch_bounds__(256) void pv_bij_kernel(
    const float* __restrict__ vpre, const float* __restrict__ ssp,
    const float* __restrict__ svp, const float* __restrict__ prim2T,
    const float* __restrict__ W, const float* __restrict__ Wb,
    float* __restrict__ bij, int first) {
  __shared__ float ps[32 * 260];      // [flat_l][b] padded
  __shared__ float vs[2 * 16 * 260];  // [cl][k][b] padded
  __shared__ float Ps[32][32];        // [flat_l][slot*16+k]
  __shared__ float scl[2];
  __shared__ float svl[2][16];
  int blk = blockIdx.x, tid = threadIdx.x;
  int loc0 = blk * 4;
  int I = (loc0 * 10) / 1152;
  if (tid < 2) {
    int cls = I + tid;
    float ss = 0.f;
    if (cls <= 9)
      for (int q = 0; q < 16; ++q) ss += ssp[cls * 16 + q];
    float nrm = sqrtf(ss);
    scl[tid] = (cls <= 9 && nrm > 0.f) ? nrm / (1.f + nrm * nrm) : 0.f;
  }
  if (tid < 32) {
    int cl = tid >> 4, k = tid & 15;
    int cls = I + cl;
    float s = 0.f;
    if (cls <= 9)
      for (int q = 0; q < 16; ++q) s += svp[(size_t)(cls * 16 + q) * 16 + k];
    svl[cl][k] = s;
  }
  for (int t = tid; t < 2048; t += 256) {
    int row = t >> 6, seg = t & 63;
    float4 a = *(const float4*)(prim2T + (size_t)(loc0 * 8 + row) * 256 + seg * 4);
    *(float4*)&ps[row * 260 + seg * 4] = a;
  }
  __syncthreads();
  for (int cl = 0; cl < 2; ++cl) {
    int cls = I + cl;
    float sc = scl[cl];
    for (int t = tid; t < 4096; t += 256) {
      int b = t >> 4, k = t & 15;
      float val = (cls <= 9) ? vpre[(size_t)cls * 4096 + t] * sc : 0.f;
      vs[(cl * 16 + k) * 260 + b] = val;
    }
  }
  __syncthreads();
  {
    int k = tid & 15, fs = tid >> 4;
    const float4* ps4 = (const float4*)ps;
    const float4* vs4 = (const float4*)vs;
#pragma unroll
    for (int q = 0; q < 4; ++q) {
      int flat_l = fs * 2 + (q & 1);
      int slot = q >> 1;
      int loc = loc0 + (flat_l >> 3);
      int cls = (loc * 10) / 1152 + slot;
      int cl_idx = cls - I;
      if (cl_idx <= 1 && cls <= 9) {
        float a = 0.f;
        int bp = flat_l * 65, bv = (cl_idx * 16 + k) * 65;
        for (int b4 = 0; b4 < 64; ++b4) {
          float4 p4 = ps4[bp + b4];
          float4 w4 = vs4[bv + b4];
          a += p4.x * w4.x + p4.y * w4.y + p4.z * w4.z + p4.w * w4.w;
        }
        Ps[flat_l][slot * 16 + k] = a;
      }
    }
  }
  __syncthreads();
  if (tid < 40) {
    int ll = tid / 10, io = tid % 10;
    int loc = loc0 + ll;
    int m = loc * 10 + io;
    int i = m / 1152;
    int slot = i - (loc * 10) / 1152;
    int cl = i - I;
    const float* wrow = W + (size_t)io * 147456 + (size_t)loc * 128;
    float s = 0.f;
#pragma unroll
    for (int k = 0; k < 16; ++k) {
      float4 w0 = *(const float4*)(wrow + k * 8);
      float4 w1 = *(const float4*)(wrow + k * 8 + 4);
      s += w0.x * Ps[ll * 8 + 0][slot * 16 + k] + w0.y * Ps[ll * 8 + 1][slot * 16 + k]
         + w0.z * Ps[ll * 8 + 2][slot * 16 + k] + w0.w * Ps[ll * 8 + 3][slot * 16 + k];
      s += w1.x * Ps[ll * 8 + 4][slot * 16 + k] + w1.y * Ps[ll * 8 + 5][slot * 16 + k]
         + w1.z * Ps[ll * 8 + 6][slot * 16 + k] + w1.w * Ps[ll * 8 + 7][slot * 16 + k];
    }
    const float* wbr = Wb + (size_t)io * 18432 + (size_t)loc * 16;
    float scsv = scl[cl];
#pragma unroll
    for (int k = 0; k < 16; ++k) s += wbr[k] * (scsv * svl[cl][k]);
    bij[m] = first ? s : (bij[m] + s);
  }
}

// ---------------- outw: final squash + output write ----------------
__global__ __launch_bounds__(256) void outw_kernel(
    const float* __restrict__ vpre, const float* __restrict__ ssp,
    float* __restrict__ out) {
  int i = blockIdx.x, tid = threadIdx.x;
  float ss = 0.f;
  for (int q = 0; q < 16; ++q) ss += ssp[i * 16 + q];
  float nrm = sqrtf(ss);
  float scale = (nrm > 0.f) ? nrm / (1.f + nrm * nrm) : 0.f;
  for (int t = tid; t < 4096; t += 256)
    out[(size_t)i * 4096 + t] = vpre[(size_t)i * 4096 + t] * scale;
}

extern "C" void kernel_launch(void* const* d_in, const int* in_sizes, int n_in,
                              void* d_out, int out_size, void* d_ws, size_t ws_size,
                              hipStream_t stream) {
  const float* x  = (const float*)d_in[0];
  const float* w1 = (const float*)d_in[1];
  const float* b1 = (const float*)d_in[2];
  const float* w2 = (const float*)d_in[3];
  const float* b2 = (const float*)d_in[4];
  const float* W  = (const float*)d_in[5];
  const float* Wb = (const float*)d_in[6];
  float* out = (float*)d_out;

  // workspace layout (~110 MB)
  u16*   hT     = (u16*)d_ws;                    // 26,214,400 u16
  u16*   w2bT   = hT + 26214400;                 //  5,308,416 u16
  u16*   pp     = w2bT + 5308416;                //  7*2,359,296 u16 (bf16 partials)
  float* prim2T = (float*)(pp + 7 * 2359296);    //  2,359,296 f
  float* vp     = prim2T + 2359296;              //  1,310,720 f
  float* vpre   = vp + 1310720;                  //     40,960 f
  float* bij    = vpre + 40960;                  //     11,520 f
  float* ssp    = bij + 11520;                   //        160 f
  float* svp    = ssp + 160;                     //      2,560 f
  float* cbp    = svp + 2560;                    //      5,120 f

  pre_kernel<<<512, 256, 0, stream>>>(x, w1, b1, w2, hT, w2bT);
  conv2_mfma_kernel<<<252, 512, 0, stream>>>(hT, w2bT, pp);

  for (int r = 0; r < 3; ++r) {
    cwvgemm_kernel<<<dim3(32, 10), 256, 0, stream>>>(bij, W, Wb, pp, b2, prim2T, vp, cbp,
                                                     r == 0 ? 1 : 0);
    vred_kernel<<<dim3(16, 10), 256, 0, stream>>>(vp, cbp, vpre, ssp, svp);
    if (r < 2) {
      pv_bij_kernel<<<288, 256, 0, stream>>>(vpre, ssp, svp, prim2T, W, Wb, bij,
                                             r == 0 ? 1 : 0);
    } else {
      outw_kernel<<<10, 256, 0, stream>>>(vpre, ssp, out);
    }
  }
}